// Round 7
// baseline (104.915 us; speedup 1.0000x reference)
//
#include <hip/hip_runtime.h>
#include <hip/hip_bf16.h>
#include <math.h>

#define BSZ 4
#define NN 512
#define DD 64
#define NKEEP 256

typedef __attribute__((ext_vector_type(8))) short short8;
typedef __attribute__((ext_vector_type(4))) float f32x4;

__device__ __forceinline__ ushort f2bf_rne(float f) {
  union { float f; unsigned u; } v; v.f = f;
  unsigned r = v.u + 0x7fffu + ((v.u >> 16) & 1u);
  return (ushort)(r >> 16);
}
__device__ __forceinline__ float bf2f(ushort h) {
  union { unsigned u; float f; } v; v.u = ((unsigned)h) << 16;
  return v.f;
}
__device__ __forceinline__ float fast_tanh(float x) {
  float e = __builtin_amdgcn_exp2f(x * 2.8853900817779268f);
  float r = __builtin_amdgcn_rcpf(e + 1.0f);
  return 1.0f - 2.0f * r;
}

// ============ Kernel P: x -> xT hi/lo split, [b][d][j] bf16 ==================
__global__ __launch_bounds__(256) void k_prep_xt(
    const float* __restrict__ x, ushort* __restrict__ xth,
    ushort* __restrict__ xtl) {
  const int b = blockIdx.x >> 3, dg = blockIdx.x & 7;
  const int t = threadIdx.x;
  const int d = dg * 8 + (t >> 5);
  const int j0 = (t & 31) * 16;
  const float* xb = x + (size_t)b * NN * DD;
  ushort th[16], tl[16];
  #pragma unroll
  for (int q = 0; q < 16; ++q) {
    const float v = xb[(size_t)(j0 + q) * DD + d];
    th[q] = f2bf_rne(v);
    tl[q] = f2bf_rne(v - bf2f(th[q]));
  }
  ushort* ph = xth + ((size_t)b * DD + d) * NN + j0;
  ushort* pl = xtl + ((size_t)b * DD + d) * NN + j0;
  #pragma unroll
  for (int q = 0; q < 16; ++q) { ph[q] = th[q]; pl[q] = tl[q]; }
}

// ============ Kernel A: symmetric scores, compact grid, 4 blocks/CU ==========
// 320 working tiles per launch: bid -> (b, it, jq) with jq*128+128 > it*16.
__global__ __launch_bounds__(256, 4) void k_score(
    const float* __restrict__ x, const float* __restrict__ apw,
    const float* __restrict__ apb, const float* __restrict__ aw,
    float* __restrict__ sT) {
  __shared__ ushort Yh[8 * 16 * 64];  // 16 KB, swizzled
  __shared__ ushort Yl[8 * 16 * 64];  // 16 KB

  const int t = threadIdx.x;
  const int w = t >> 6, l = t & 63;
  const int tid = blockIdx.x % 80;
  const int b = blockIdx.x / 80;
  int jq, it;
  if (tid < 8)        { jq = 0; it = tid; }
  else if (tid < 24)  { jq = 1; it = tid - 8; }
  else if (tid < 48)  { jq = 2; it = tid - 24; }
  else                { jq = 3; it = tid - 48; }
  const int i0 = it * 16;
  const int jb0 = jq * 128;
  const bool fast = (jb0 >= i0 + 16);

  const float* xb = x + (size_t)b * NN * DD;
  const int j0 = jb0 + w * 32;
  const bool wave_active = (j0 + 32 > i0);

  // ---- Xi slice into registers for Y-build ----
  const int p_e = t >> 5;            // e sub-index 0..7
  const int q = t & 31;
  const int ih = (q >> 4) * 8;       // i base (0 or 8)
  const int d0 = (q & 15) * 4;       // d quad base
  float xi_r[8][4];
  #pragma unroll
  for (int i2 = 0; i2 < 8; ++i2) {
    float4 v = *reinterpret_cast<const float4*>(xb + (size_t)(i0 + ih + i2) * DD + d0);
    xi_r[i2][0] = v.x; xi_r[i2][1] = v.y; xi_r[i2][2] = v.z; xi_r[i2][3] = v.w;
  }

  // ---- A fragments (Xj) split hi/lo, e-independent ----
  short8 ah[2][2], al[2][2];
  if (wave_active) {
    const int g = l >> 4;
    #pragma unroll
    for (int jt = 0; jt < 2; ++jt) {
      const int j = j0 + jt * 16 + (l & 15);
      #pragma unroll
      for (int ks = 0; ks < 2; ++ks) {
        const float* xr = xb + (size_t)j * DD + ks * 32 + g * 8;
        float4 u0 = *reinterpret_cast<const float4*>(xr);
        float4 u1 = *reinterpret_cast<const float4*>(xr + 4);
        float vv[8] = {u0.x, u0.y, u0.z, u0.w, u1.x, u1.y, u1.z, u1.w};
        short8 hh, ll;
        #pragma unroll
        for (int qq = 0; qq < 8; ++qq) {
          ushort hq = f2bf_rne(vv[qq]);
          hh[qq] = (short)hq;
          ll[qq] = (short)f2bf_rne(vv[qq] - bf2f(hq));
        }
        ah[jt][ks] = hh; al[jt][ks] = ll;
      }
    }
  }

  auto build = [&](int rnd) {
    const int e = rnd * 8 + p_e;
    float wt[4];
    #pragma unroll
    for (int k = 0; k < 4; ++k) wt[k] = apw[(d0 + k) * 64 + e];
    #pragma unroll
    for (int i2 = 0; i2 < 8; ++i2) {
      const int i = ih + i2;
      ushort h4[4], l4[4];
      #pragma unroll
      for (int k = 0; k < 4; ++k) {
        const float v = xi_r[i2][k] * wt[k];
        h4[k] = f2bf_rne(v);
        l4[k] = f2bf_rne(v - bf2f(h4[k]));
      }
      uint2 hw, lw;
      hw.x = (uint)h4[0] | ((uint)h4[1] << 16);
      hw.y = (uint)h4[2] | ((uint)h4[3] << 16);
      lw.x = (uint)l4[0] | ((uint)l4[1] << 16);
      lw.y = (uint)l4[2] | ((uint)l4[3] << 16);
      const int byteoff = (p_e * 2048 + (i * 64 + d0) * 2) ^ ((i & 7) << 4);
      *reinterpret_cast<uint2*>(reinterpret_cast<char*>(Yh) + byteoff) = hw;
      *reinterpret_cast<uint2*>(reinterpret_cast<char*>(Yl) + byteoff) = lw;
    }
  };

  f32x4 srews[2];
  srews[0] = (f32x4){0.f, 0.f, 0.f, 0.f};
  srews[1] = (f32x4){0.f, 0.f, 0.f, 0.f};

  build(0);

  #pragma unroll 1
  for (int r = 0; r < 8; ++r) {
    __syncthreads();                 // Y(r) visible
    if (wave_active) {
      const char* Ph = reinterpret_cast<const char*>(Yh);
      const char* Pl = reinterpret_cast<const char*>(Yl);
      const int il = l & 15, g = l >> 4;
      #pragma unroll
      for (int p = 0; p < 8; ++p) {
        const int e = r * 8 + p;
        short8 bh[2], bl[2];
        #pragma unroll
        for (int ks = 0; ks < 2; ++ks) {
          const int byteoff =
              (p * 2048 + (il * 64 + ks * 32 + g * 8) * 2) ^ ((il & 7) << 4);
          bh[ks] = *reinterpret_cast<const short8*>(Ph + byteoff);
          bl[ks] = *reinterpret_cast<const short8*>(Pl + byteoff);
        }
        f32x4 acc[2];
        acc[0] = (f32x4){0.f, 0.f, 0.f, 0.f};
        acc[1] = (f32x4){0.f, 0.f, 0.f, 0.f};
        #pragma unroll
        for (int jt = 0; jt < 2; ++jt)
          #pragma unroll
          for (int ks = 0; ks < 2; ++ks) {
            acc[jt] = __builtin_amdgcn_mfma_f32_16x16x32_bf16(ah[jt][ks], bh[ks], acc[jt], 0, 0, 0);
            acc[jt] = __builtin_amdgcn_mfma_f32_16x16x32_bf16(ah[jt][ks], bl[ks], acc[jt], 0, 0, 0);
            acc[jt] = __builtin_amdgcn_mfma_f32_16x16x32_bf16(al[jt][ks], bh[ks], acc[jt], 0, 0, 0);
          }
        const float bias = apb[e], awv = aw[e];
        #pragma unroll
        for (int jt = 0; jt < 2; ++jt)
          #pragma unroll
          for (int rr = 0; rr < 4; ++rr)
            srews[jt][rr] += awv * fast_tanh(acc[jt][rr] + bias);
      }
    }
    __syncthreads();                 // Y consumed
    if (r < 7) build(r + 1);
  }

  // ---- stores ----
  float* plane = sT + (size_t)b * NN * NN;
  const int il = l & 15, g = l >> 4;
  const int iv = i0 + il;
  if (fast) {
    // mirror: register-direct, 4 rows x 64B (clean pattern)
    #pragma unroll
    for (int jt = 0; jt < 2; ++jt)
      #pragma unroll
      for (int rr = 0; rr < 4; ++rr)
        plane[(size_t)(j0 + jt * 16 + g * 4 + rr) * NN + iv] = srews[jt][rr];
    // upper: transpose via swizzled LDS T[16][128] (aliases dead Yh)
    float* T = reinterpret_cast<float*>(Yh);
    #pragma unroll
    for (int jt = 0; jt < 2; ++jt)
      #pragma unroll
      for (int rr = 0; rr < 4; ++rr) {
        const int colw = w * 32 + jt * 16 + g * 4 + rr;
        const int byteoff = ((il * 128 + colw) * 4) ^ ((il & 7) << 4);
        *reinterpret_cast<float*>(reinterpret_cast<char*>(T) + byteoff) =
            srews[jt][rr];
      }
    __syncthreads();
    const int row = t >> 4, cb = (t & 15) * 8;
    const char* Tc = reinterpret_cast<const char*>(T);
    const int base = (row * 128 + cb) * 4;
    const int sw = (row & 7) << 4;
    f32x4 v0 = *reinterpret_cast<const f32x4*>(Tc + ((base) ^ sw));
    f32x4 v1 = *reinterpret_cast<const f32x4*>(Tc + ((base + 16) ^ sw));
    *reinterpret_cast<f32x4*>(plane + (size_t)(i0 + row) * NN + jb0 + cb) = v0;
    *reinterpret_cast<f32x4*>(plane + (size_t)(i0 + row) * NN + jb0 + cb + 4) = v1;
  } else if (wave_active) {
    #pragma unroll
    for (int jt = 0; jt < 2; ++jt)
      #pragma unroll
      for (int rr = 0; rr < 4; ++rr) {
        const int jv = j0 + jt * 16 + g * 4 + rr;
        const float v = srews[jt][rr];
        if (jv >= iv) plane[(size_t)iv * NN + jv] = v;
        if (jv > iv) plane[(size_t)jv * NN + iv] = v;
      }
  }
}

// ====== Kernel B: 8 rows/block; softmax + MFMA agg + h + BN + SELU + s =======
__global__ __launch_bounds__(256) void k_soft(
    const float* __restrict__ x, const float* __restrict__ sT,
    const ushort* __restrict__ xth, const ushort* __restrict__ xtl,
    const float* __restrict__ pwa, const float* __restrict__ pwab,
    const float* __restrict__ pwoa, const float* __restrict__ pwob,
    const float* __restrict__ gam, const float* __restrict__ bet,
    const float* __restrict__ mu, const float* __restrict__ var,
    const float* __restrict__ poolw, const float* __restrict__ poolb,
    float* __restrict__ h, float* __restrict__ s) {
  __shared__ ushort att_h[16 * 512];   // 16 KB, swizzled (rows 8..15 unused)
  __shared__ ushort att_l[16 * 512];   // 16 KB
  __shared__ float aggp[4][8][64];     // 8 KB
  __shared__ float shm2[4][2][2][64];  // 4 KB [wave][row][{agg,xi}][d]

  const int t = threadIdx.x;
  const int w = t >> 6, l = t & 63;
  const int b = blockIdx.x >> 6;
  const int ig = blockIdx.x & 63;
  const int m0 = w * 2, m1 = m0 + 1;        // tile-local rows
  const int i_r0 = ig * 8 + m0, i_r1 = i_r0 + 1;
  const float* xb = x + (size_t)b * NN * DD;
  const float* plane = sT + (size_t)b * NN * NN;

  // ---- P1: softmax of rows i_r0, i_r1 (att kept in registers) ----
  float a0[8], a1[8];
  #pragma unroll
  for (int k = 0; k < 8; ++k) {
    a0[k] = plane[(size_t)i_r0 * NN + k * 64 + l];
    a1[k] = plane[(size_t)i_r1 * NN + k * 64 + l];
  }
  float mx0 = a0[0], mx1 = a1[0];
  #pragma unroll
  for (int k = 1; k < 8; ++k) { mx0 = fmaxf(mx0, a0[k]); mx1 = fmaxf(mx1, a1[k]); }
  #pragma unroll
  for (int off = 32; off; off >>= 1) {
    mx0 = fmaxf(mx0, __shfl_xor(mx0, off, 64));
    mx1 = fmaxf(mx1, __shfl_xor(mx1, off, 64));
  }
  const float L2E = 1.4426950408889634f;
  float ps0 = 0.f, ps1 = 0.f;
  #pragma unroll
  for (int k = 0; k < 8; ++k) {
    a0[k] = __builtin_amdgcn_exp2f((a0[k] - mx0) * L2E);
    a1[k] = __builtin_amdgcn_exp2f((a1[k] - mx1) * L2E);
    ps0 += a0[k]; ps1 += a1[k];
  }
  #pragma unroll
  for (int off = 32; off; off >>= 1) {
    ps0 += __shfl_xor(ps0, off, 64);
    ps1 += __shfl_xor(ps1, off, 64);
  }
  const float inv0 = 1.f / ps0, inv1 = 1.f / ps1;

  // ---- att -> swizzled LDS, split hi/lo ----
  #pragma unroll
  for (int k = 0; k < 8; ++k) {
    const float v0 = a0[k] * inv0, v1 = a1[k] * inv1;
    const ushort h0 = f2bf_rne(v0), h1 = f2bf_rne(v1);
    const ushort lo0 = f2bf_rne(v0 - bf2f(h0)), lo1 = f2bf_rne(v1 - bf2f(h1));
    const int c = (k * 64 + l) * 2;
    const int o0 = (m0 * 1024 + c) ^ ((m0 & 7) << 4);
    const int o1 = (m1 * 1024 + c) ^ ((m1 & 7) << 4);
    *reinterpret_cast<ushort*>(reinterpret_cast<char*>(att_h) + o0) = h0;
    *reinterpret_cast<ushort*>(reinterpret_cast<char*>(att_l) + o0) = lo0;
    *reinterpret_cast<ushort*>(reinterpret_cast<char*>(att_h) + o1) = h1;
    *reinterpret_cast<ushort*>(reinterpret_cast<char*>(att_l) + o1) = lo1;
  }
  __syncthreads();

  // ---- P2: agg = att @ x via split-bf16 MFMA; wave w owns K=[w*128,+128) ----
  const int il = l & 15, g = l >> 4;
  f32x4 acc[4];
  #pragma unroll
  for (int nt = 0; nt < 4; ++nt) acc[nt] = (f32x4){0.f, 0.f, 0.f, 0.f};
  #pragma unroll
  for (int kk = 0; kk < 4; ++kk) {
    const int ks = w * 4 + kk;
    const int koff = ks * 32 + g * 8;
    const int abyte = (il * 1024 + koff * 2) ^ ((il & 7) << 4);
    short8 fa_h = *reinterpret_cast<const short8*>(
        reinterpret_cast<const char*>(att_h) + abyte);
    short8 fa_l = *reinterpret_cast<const short8*>(
        reinterpret_cast<const char*>(att_l) + abyte);
    #pragma unroll
    for (int nt = 0; nt < 4; ++nt) {
      const size_t xoff = ((size_t)b * DD + nt * 16 + il) * NN + koff;
      short8 fb_h = *reinterpret_cast<const short8*>(xth + xoff);
      short8 fb_l = *reinterpret_cast<const short8*>(xtl + xoff);
      acc[nt] = __builtin_amdgcn_mfma_f32_16x16x32_bf16(fa_h, fb_h, acc[nt], 0, 0, 0);
      acc[nt] = __builtin_amdgcn_mfma_f32_16x16x32_bf16(fa_h, fb_l, acc[nt], 0, 0, 0);
      acc[nt] = __builtin_amdgcn_mfma_f32_16x16x32_bf16(fa_l, fb_h, acc[nt], 0, 0, 0);
    }
  }
  // partials: D row = g*4+reg (only g<2 rows are real), col = nt*16+il
  if (g < 2) {
    #pragma unroll
    for (int nt = 0; nt < 4; ++nt)
      #pragma unroll
      for (int rr = 0; rr < 4; ++rr)
        aggp[w][g * 4 + rr][nt * 16 + il] = acc[nt][rr];
  }
  __syncthreads();

  // ---- P3: h = agg@pwa + xi@pwoa (+biases), BN, SELU, pool ----
  float g0 = aggp[0][m0][l] + aggp[1][m0][l] + aggp[2][m0][l] + aggp[3][m0][l];
  float g1 = aggp[0][m1][l] + aggp[1][m1][l] + aggp[2][m1][l] + aggp[3][m1][l];
  shm2[w][0][0][l] = g0;
  shm2[w][1][0][l] = g1;
  shm2[w][0][1][l] = xb[(size_t)i_r0 * DD + l];
  shm2[w][1][1][l] = xb[(size_t)i_r1 * DD + l];
  float acc0 = 0.f, acc1 = 0.f;
  #pragma unroll 8
  for (int d = 0; d < 64; ++d) {
    const float wa = pwa[d * 64 + l], wo = pwoa[d * 64 + l];
    acc0 = fmaf(shm2[w][0][0][d], wa, acc0);
    acc0 = fmaf(shm2[w][0][1][d], wo, acc0);
    acc1 = fmaf(shm2[w][1][0][d], wa, acc1);
    acc1 = fmaf(shm2[w][1][1][d], wo, acc1);
  }
  const float bsum = pwab[l] + pwob[l];
  acc0 += bsum; acc1 += bsum;
  const float bnscale = rsqrtf(var[l] + 1e-5f) * gam[l];
  const float bnm = mu[l], bnb = bet[l];
  float hb0 = (acc0 - bnm) * bnscale + bnb;
  float hb1 = (acc1 - bnm) * bnscale + bnb;
  const float SC = 1.0507009873554805f, AL = 1.6732632423543772f;
  float hv0 = hb0 > 0.f ? SC * hb0 : SC * AL * expm1f(hb0);
  float hv1 = hb1 > 0.f ? SC * hb1 : SC * AL * expm1f(hb1);
  h[((size_t)(b * NN + i_r0)) * DD + l] = hv0;
  h[((size_t)(b * NN + i_r1)) * DD + l] = hv1;

  float p0 = hv0 * poolw[l], p1 = hv1 * poolw[l];
  #pragma unroll
  for (int off = 32; off; off >>= 1) {
    p0 += __shfl_xor(p0, off, 64);
    p1 += __shfl_xor(p1, off, 64);
  }
  if (l == 0) {
    s[b * NN + i_r0] = 1.f / (1.f + expf(-(p0 + poolb[0])));
    s[b * NN + i_r1] = 1.f / (1.f + expf(-(p1 + poolb[0])));
  }
}

// ====== Kernel C: per-batch top-k via rank selection (exact tie semantics) ===
__global__ __launch_bounds__(512) void k_topk(
    const float* __restrict__ s, const float* __restrict__ h,
    float* __restrict__ out) {
  __shared__ float sv[NN];
  __shared__ int inv[NKEEP];
  const int b = blockIdx.x, t = threadIdx.x;
  sv[t] = s[b * NN + t];
  __syncthreads();

  const float my = sv[t];
  int r = 0;
  #pragma unroll 4
  for (int j0 = 0; j0 < NN; j0 += 4) {
    float4 v = *reinterpret_cast<const float4*>(&sv[j0]);
    r += (v.x > my) || (v.x == my && (j0 + 0) < t);
    r += (v.y > my) || (v.y == my && (j0 + 1) < t);
    r += (v.z > my) || (v.z == my && (j0 + 2) < t);
    r += (v.w > my) || (v.w == my && (j0 + 3) < t);
  }
  if (r < NKEEP) inv[r] = t;
  __syncthreads();

  for (int pos = t; pos < NKEEP * DD; pos += 512) {
    const int kk = pos >> 6, d = pos & 63;
    const int i = inv[kk];
    out[((size_t)b * NKEEP + kk) * DD + d] =
        h[((size_t)b * NN + i) * DD + d] * sv[i];
  }
}

extern "C" void kernel_launch(void* const* d_in, const int* in_sizes, int n_in,
                              void* d_out, int out_size, void* d_ws, size_t ws_size,
                              hipStream_t stream) {
  const float* x     = (const float*)d_in[0];
  const float* apw   = (const float*)d_in[1];
  const float* apb   = (const float*)d_in[2];
  const float* aw    = (const float*)d_in[3];
  const float* pwa   = (const float*)d_in[4];
  const float* pwab  = (const float*)d_in[5];
  const float* pwoa  = (const float*)d_in[6];
  const float* pwob  = (const float*)d_in[7];
  const float* gam   = (const float*)d_in[8];
  const float* bet   = (const float*)d_in[9];
  const float* mu    = (const float*)d_in[10];
  const float* var   = (const float*)d_in[11];
  const float* poolw = (const float*)d_in[12];
  const float* poolb = (const float*)d_in[13];
  float* out = (float*)d_out;

  float* sT   = (float*)d_ws;                       // 4 MB
  float* h    = sT + (size_t)BSZ * NN * NN;         // 512 KB
  float* s    = h + (size_t)BSZ * NN * DD;          // 8 KB
  ushort* xth = (ushort*)(s + BSZ * NN);            // 256 KB
  ushort* xtl = xth + (size_t)BSZ * DD * NN;        // 256 KB

  k_prep_xt<<<32, 256, 0, stream>>>(x, xth, xtl);
  k_score<<<320, 256, 0, stream>>>(x, apw, apb, aw, sT);
  k_soft<<<BSZ * 64, 256, 0, stream>>>(x, sT, xth, xtl, pwa, pwab, pwoa, pwob,
                                       gam, bet, mu, var, poolw, poolb, h, s);
  k_topk<<<BSZ, 512, 0, stream>>>(s, h, out);
}

// Round 8
// 69.181 us; speedup vs baseline: 1.5165x; 1.5165x over previous
//
#include <hip/hip_runtime.h>
#include <hip/hip_bf16.h>
#include <math.h>

#define BSZ 4
#define NN 512
#define DD 64
#define NKEEP 256

typedef __attribute__((ext_vector_type(8))) short short8;
typedef __attribute__((ext_vector_type(4))) float f32x4;

__device__ __forceinline__ ushort f2bf_rne(float f) {
  union { float f; unsigned u; } v; v.f = f;
  unsigned r = v.u + 0x7fffu + ((v.u >> 16) & 1u);
  return (ushort)(r >> 16);
}
__device__ __forceinline__ float bf2f(ushort h) {
  union { unsigned u; float f; } v; v.u = ((unsigned)h) << 16;
  return v.f;
}
__device__ __forceinline__ float fast_tanh(float x) {
  float e = __builtin_amdgcn_exp2f(x * 2.8853900817779268f);
  float r = __builtin_amdgcn_rcpf(e + 1.0f);
  return 1.0f - 2.0f * r;
}

// ============ Kernel A: symmetric partial scores, e-split x2 ================
// grid = 640: bid -> (b:4, eh:2, tile:80); tile -> (jq,it) with jq*128+128>it*16.
// Block: i-tile 16, j-range 128 (4 waves x 32 j), e-range [eh*32,+32) in 4
// rounds of 8.  Partial scores to plane sTp[eh*4+b]; upper rows via LDS
// transpose, mirror register-direct (both R6-proven coalesced patterns).
__global__ __launch_bounds__(256, 2) void k_score(
    const float* __restrict__ x, const float* __restrict__ apw,
    const float* __restrict__ apb, const float* __restrict__ aw,
    float* __restrict__ sTp) {
  __shared__ float Xi_s[16 * 64];     // 4 KB
  __shared__ ushort Yh[8 * 16 * 64];  // 16 KB, swizzled
  __shared__ ushort Yl[8 * 16 * 64];  // 16 KB

  const int t = threadIdx.x;
  const int w = t >> 6, l = t & 63;
  const int b = blockIdx.x / 160;
  const int rem = blockIdx.x % 160;
  const int eh = rem / 80;
  const int tid = rem % 80;
  int jq, it;
  if (tid < 8)        { jq = 0; it = tid; }
  else if (tid < 24)  { jq = 1; it = tid - 8; }
  else if (tid < 48)  { jq = 2; it = tid - 24; }
  else                { jq = 3; it = tid - 48; }
  const int i0 = it * 16;
  const int jb0 = jq * 128;
  const int eh32 = eh * 32;
  const bool fast = (jb0 >= i0 + 16);

  const float* xb = x + (size_t)b * NN * DD;
  const int j0 = jb0 + w * 32;
  const bool wave_active = (j0 + 32 > i0);

  // ---- stage Xi into LDS (16 x 64 fp32) ----
  {
    const int row = t >> 4, dq = (t & 15) * 4;
    *reinterpret_cast<float4*>(&Xi_s[row * 64 + dq]) =
        *reinterpret_cast<const float4*>(xb + (size_t)(i0 + row) * DD + dq);
  }

  // ---- A fragments (Xj) split hi/lo, e-independent ----
  short8 ah[2][2], al[2][2];
  if (wave_active) {
    const int g = l >> 4;
    #pragma unroll
    for (int jt = 0; jt < 2; ++jt) {
      const int j = j0 + jt * 16 + (l & 15);
      #pragma unroll
      for (int ks = 0; ks < 2; ++ks) {
        const float* xr = xb + (size_t)j * DD + ks * 32 + g * 8;
        float4 u0 = *reinterpret_cast<const float4*>(xr);
        float4 u1 = *reinterpret_cast<const float4*>(xr + 4);
        float vv[8] = {u0.x, u0.y, u0.z, u0.w, u1.x, u1.y, u1.z, u1.w};
        short8 hh, ll;
        #pragma unroll
        for (int qq = 0; qq < 8; ++qq) {
          ushort hq = f2bf_rne(vv[qq]);
          hh[qq] = (short)hq;
          ll[qq] = (short)f2bf_rne(vv[qq] - bf2f(hq));
        }
        ah[jt][ks] = hh; al[jt][ks] = ll;
      }
    }
  }

  const int p_e = t >> 5;            // Y-build: e sub-index 0..7
  const int q = t & 31;
  const int ih = (q >> 4) * 8;       // i base (0 or 8)
  const int d0 = (q & 15) * 4;       // d quad base

  auto build = [&](int rnd) {
    const int e = eh32 + rnd * 8 + p_e;
    float wt[4];
    #pragma unroll
    for (int k = 0; k < 4; ++k) wt[k] = apw[(d0 + k) * 64 + e];
    #pragma unroll
    for (int i2 = 0; i2 < 8; ++i2) {
      const int i = ih + i2;
      float4 xv = *reinterpret_cast<const float4*>(&Xi_s[i * 64 + d0]);
      const float p0v = xv.x * wt[0], p1v = xv.y * wt[1];
      const float p2v = xv.z * wt[2], p3v = xv.w * wt[3];
      const ushort h0 = f2bf_rne(p0v), h1 = f2bf_rne(p1v);
      const ushort h2 = f2bf_rne(p2v), h3 = f2bf_rne(p3v);
      uint2 hw, lw;
      hw.x = (uint)h0 | ((uint)h1 << 16);
      hw.y = (uint)h2 | ((uint)h3 << 16);
      lw.x = (uint)f2bf_rne(p0v - bf2f(h0)) | ((uint)f2bf_rne(p1v - bf2f(h1)) << 16);
      lw.y = (uint)f2bf_rne(p2v - bf2f(h2)) | ((uint)f2bf_rne(p3v - bf2f(h3)) << 16);
      const int byteoff = (p_e * 2048 + (i * 64 + d0) * 2) ^ ((i & 7) << 4);
      *reinterpret_cast<uint2*>(reinterpret_cast<char*>(Yh) + byteoff) = hw;
      *reinterpret_cast<uint2*>(reinterpret_cast<char*>(Yl) + byteoff) = lw;
    }
  };

  f32x4 srews[2];
  srews[0] = (f32x4){0.f, 0.f, 0.f, 0.f};
  srews[1] = (f32x4){0.f, 0.f, 0.f, 0.f};

  __syncthreads();  // Xi_s visible
  build(0);

  #pragma unroll 1
  for (int r = 0; r < 4; ++r) {
    __syncthreads();  // Y(r) visible
    if (wave_active) {
      const char* Ph = reinterpret_cast<const char*>(Yh);
      const char* Pl = reinterpret_cast<const char*>(Yl);
      const int il = l & 15, g = l >> 4;
      #pragma unroll
      for (int p = 0; p < 8; ++p) {
        const int e = eh32 + r * 8 + p;
        short8 bh[2], bl[2];
        #pragma unroll
        for (int ks = 0; ks < 2; ++ks) {
          const int byteoff =
              (p * 2048 + (il * 64 + ks * 32 + g * 8) * 2) ^ ((il & 7) << 4);
          bh[ks] = *reinterpret_cast<const short8*>(Ph + byteoff);
          bl[ks] = *reinterpret_cast<const short8*>(Pl + byteoff);
        }
        f32x4 acc[2];
        acc[0] = (f32x4){0.f, 0.f, 0.f, 0.f};
        acc[1] = (f32x4){0.f, 0.f, 0.f, 0.f};
        #pragma unroll
        for (int jt = 0; jt < 2; ++jt)
          #pragma unroll
          for (int ks = 0; ks < 2; ++ks) {
            acc[jt] = __builtin_amdgcn_mfma_f32_16x16x32_bf16(ah[jt][ks], bh[ks], acc[jt], 0, 0, 0);
            acc[jt] = __builtin_amdgcn_mfma_f32_16x16x32_bf16(ah[jt][ks], bl[ks], acc[jt], 0, 0, 0);
            acc[jt] = __builtin_amdgcn_mfma_f32_16x16x32_bf16(al[jt][ks], bh[ks], acc[jt], 0, 0, 0);
          }
        const float bias = apb[e], awv = aw[e];
        #pragma unroll
        for (int jt = 0; jt < 2; ++jt)
          #pragma unroll
          for (int rr = 0; rr < 4; ++rr)
            srews[jt][rr] += awv * fast_tanh(acc[jt][rr] + bias);
      }
    }
    __syncthreads();  // Y consumed
    if (r < 3) build(r + 1);
  }

  // ---- stores (all waves synced above) ----
  float* plane = sTp + ((size_t)(eh * 4 + b)) * NN * NN;
  const int il = l & 15, g = l >> 4;
  const int iv = i0 + il;
  if (fast) {
    // mirror: register-direct, 4 rows x 64B (clean)
    #pragma unroll
    for (int jt = 0; jt < 2; ++jt)
      #pragma unroll
      for (int rr = 0; rr < 4; ++rr)
        plane[(size_t)(j0 + jt * 16 + g * 4 + rr) * NN + iv] = srews[jt][rr];
    // upper: transpose via swizzled LDS T[16][128] (aliases dead Yh)
    float* T = reinterpret_cast<float*>(Yh);
    #pragma unroll
    for (int jt = 0; jt < 2; ++jt)
      #pragma unroll
      for (int rr = 0; rr < 4; ++rr) {
        const int colw = w * 32 + jt * 16 + g * 4 + rr;
        const int byteoff = ((il * 128 + colw) * 4) ^ ((il & 7) << 4);
        *reinterpret_cast<float*>(reinterpret_cast<char*>(T) + byteoff) =
            srews[jt][rr];
      }
    __syncthreads();
    const int row = t >> 4, cb = (t & 15) * 8;
    const char* Tc = reinterpret_cast<const char*>(T);
    const int base = (row * 128 + cb) * 4;
    const int sw = (row & 7) << 4;
    f32x4 v0 = *reinterpret_cast<const f32x4*>(Tc + ((base) ^ sw));
    f32x4 v1 = *reinterpret_cast<const f32x4*>(Tc + ((base + 16) ^ sw));
    *reinterpret_cast<f32x4*>(plane + (size_t)(i0 + row) * NN + jb0 + cb) = v0;
    *reinterpret_cast<f32x4*>(plane + (size_t)(i0 + row) * NN + jb0 + cb + 4) = v1;
  } else if (wave_active) {
    #pragma unroll
    for (int jt = 0; jt < 2; ++jt)
      #pragma unroll
      for (int rr = 0; rr < 4; ++rr) {
        const int jv = j0 + jt * 16 + g * 4 + rr;
        const float v = srews[jt][rr];
        if (jv >= iv) plane[(size_t)iv * NN + jv] = v;
        if (jv > iv) plane[(size_t)jv * NN + iv] = v;
      }
  }
}

// ====== Kernel B: 2 rows/block, 4 waves j-split: softmax+agg+h+BN+SELU+s =====
__global__ __launch_bounds__(256) void k_soft(
    const float* __restrict__ x, const float* __restrict__ sTp,
    const float* __restrict__ pwa, const float* __restrict__ pwab,
    const float* __restrict__ pwoa, const float* __restrict__ pwob,
    const float* __restrict__ gam, const float* __restrict__ bet,
    const float* __restrict__ mu, const float* __restrict__ var,
    const float* __restrict__ poolw, const float* __restrict__ poolb,
    float* __restrict__ h, float* __restrict__ s) {
  __shared__ float ssc[2][512];       // 4 KB: att weights
  __shared__ float srm[2][4], srs[2][4];
  __shared__ float sagg[4][2][64];    // 2 KB
  __shared__ float rag[2][64], xis[2][64];

  const int t = threadIdx.x;
  const int w = t >> 6, l = t & 63;
  const int b = blockIdx.x >> 8;
  const int rp = blockIdx.x & 255;
  const int i_r0 = rp * 2, i_r1 = i_r0 + 1;
  const float* xb = x + (size_t)b * NN * DD;
  const float* pl0 = sTp + (size_t)b * NN * NN;
  const float* pl1 = sTp + (size_t)(4 + b) * NN * NN;
  const int jw = w * 128;

  // ---- softmax (wave j-split + block reduce) ----
  const size_t o0 = (size_t)i_r0 * NN + jw + l;
  const size_t o1 = (size_t)i_r1 * NN + jw + l;
  float r0a = pl0[o0] + pl1[o0];
  float r0b = pl0[o0 + 64] + pl1[o0 + 64];
  float r1a = pl0[o1] + pl1[o1];
  float r1b = pl0[o1 + 64] + pl1[o1 + 64];
  float m0 = fmaxf(r0a, r0b), m1 = fmaxf(r1a, r1b);
  #pragma unroll
  for (int off = 32; off; off >>= 1) {
    m0 = fmaxf(m0, __shfl_xor(m0, off, 64));
    m1 = fmaxf(m1, __shfl_xor(m1, off, 64));
  }
  if (l == 0) { srm[0][w] = m0; srm[1][w] = m1; }
  __syncthreads();
  m0 = fmaxf(fmaxf(srm[0][0], srm[0][1]), fmaxf(srm[0][2], srm[0][3]));
  m1 = fmaxf(fmaxf(srm[1][0], srm[1][1]), fmaxf(srm[1][2], srm[1][3]));

  const float L2E = 1.4426950408889634f;
  float e0a = __builtin_amdgcn_exp2f((r0a - m0) * L2E);
  float e0b = __builtin_amdgcn_exp2f((r0b - m0) * L2E);
  float e1a = __builtin_amdgcn_exp2f((r1a - m1) * L2E);
  float e1b = __builtin_amdgcn_exp2f((r1b - m1) * L2E);
  float ps0 = e0a + e0b, ps1 = e1a + e1b;
  #pragma unroll
  for (int off = 32; off; off >>= 1) {
    ps0 += __shfl_xor(ps0, off, 64);
    ps1 += __shfl_xor(ps1, off, 64);
  }
  if (l == 0) { srs[0][w] = ps0; srs[1][w] = ps1; }
  __syncthreads();
  const float inv0 = 1.f / (srs[0][0] + srs[0][1] + srs[0][2] + srs[0][3]);
  const float inv1 = 1.f / (srs[1][0] + srs[1][1] + srs[1][2] + srs[1][3]);
  ssc[0][jw + l] = e0a * inv0;
  ssc[0][jw + 64 + l] = e0b * inv0;
  ssc[1][jw + l] = e1a * inv1;
  ssc[1][jw + 64 + l] = e1b * inv1;
  __syncthreads();

  // ---- agg GEMV: wave covers its 128-j slice, both rows; lane owns d=l ----
  float g0 = 0.f, g1 = 0.f;
  #pragma unroll 4
  for (int jj = 0; jj < 128; ++jj) {
    const int j = jw + jj;
    const float xv = xb[(size_t)j * DD + l];
    g0 = fmaf(ssc[0][j], xv, g0);
    g1 = fmaf(ssc[1][j], xv, g1);
  }
  sagg[w][0][l] = g0;
  sagg[w][1][l] = g1;
  __syncthreads();

  // ---- P3 on waves 0/1 (one row each) ----
  if (w < 2) {
    const int irow = i_r0 + w;
    rag[w][l] = sagg[0][w][l] + sagg[1][w][l] + sagg[2][w][l] + sagg[3][w][l];
    xis[w][l] = xb[(size_t)irow * DD + l];
    // same-wave LDS write->read (cross-lane) is coherent without barrier
    float acc = 0.f;
    #pragma unroll 8
    for (int d = 0; d < 64; ++d) {
      acc = fmaf(rag[w][d], pwa[d * 64 + l], acc);
      acc = fmaf(xis[w][d], pwoa[d * 64 + l], acc);
    }
    acc += pwab[l] + pwob[l];
    float hb = (acc - mu[l]) * rsqrtf(var[l] + 1e-5f) * gam[l] + bet[l];
    const float SC = 1.0507009873554805f, AL = 1.6732632423543772f;
    float hv = hb > 0.f ? SC * hb : SC * AL * expm1f(hb);
    h[((size_t)(b * NN + irow)) * DD + l] = hv;

    float p = hv * poolw[l];
    #pragma unroll
    for (int off = 32; off; off >>= 1) p += __shfl_xor(p, off, 64);
    if (l == 0) s[b * NN + irow] = 1.f / (1.f + expf(-(p + poolb[0])));
  }
}

// ====== Kernel C: per-batch top-k via rank selection (exact tie semantics) ===
__global__ __launch_bounds__(512) void k_topk(
    const float* __restrict__ s, const float* __restrict__ h,
    float* __restrict__ out) {
  __shared__ float sv[NN];
  __shared__ int inv[NKEEP];
  const int b = blockIdx.x, t = threadIdx.x;
  sv[t] = s[b * NN + t];
  __syncthreads();

  const float my = sv[t];
  int r = 0;
  #pragma unroll 4
  for (int j0 = 0; j0 < NN; j0 += 4) {
    float4 v = *reinterpret_cast<const float4*>(&sv[j0]);
    r += (v.x > my) || (v.x == my && (j0 + 0) < t);
    r += (v.y > my) || (v.y == my && (j0 + 1) < t);
    r += (v.z > my) || (v.z == my && (j0 + 2) < t);
    r += (v.w > my) || (v.w == my && (j0 + 3) < t);
  }
  if (r < NKEEP) inv[r] = t;
  __syncthreads();

  for (int pos = t; pos < NKEEP * DD; pos += 512) {
    const int kk = pos >> 6, d = pos & 63;
    const int i = inv[kk];
    out[((size_t)b * NKEEP + kk) * DD + d] =
        h[((size_t)b * NN + i) * DD + d] * sv[i];
  }
}

extern "C" void kernel_launch(void* const* d_in, const int* in_sizes, int n_in,
                              void* d_out, int out_size, void* d_ws, size_t ws_size,
                              hipStream_t stream) {
  const float* x     = (const float*)d_in[0];
  const float* apw   = (const float*)d_in[1];
  const float* apb   = (const float*)d_in[2];
  const float* aw    = (const float*)d_in[3];
  const float* pwa   = (const float*)d_in[4];
  const float* pwab  = (const float*)d_in[5];
  const float* pwoa  = (const float*)d_in[6];
  const float* pwob  = (const float*)d_in[7];
  const float* gam   = (const float*)d_in[8];
  const float* bet   = (const float*)d_in[9];
  const float* mu    = (const float*)d_in[10];
  const float* var   = (const float*)d_in[11];
  const float* poolw = (const float*)d_in[12];
  const float* poolb = (const float*)d_in[13];
  float* out = (float*)d_out;

  float* sTp = (float*)d_ws;                      // 2 planes x 4 MB = 8 MB
  float* h   = sTp + (size_t)2 * BSZ * NN * NN;   // 512 KB
  float* s   = h + (size_t)BSZ * NN * DD;         // 8 KB

  k_score<<<640, 256, 0, stream>>>(x, apw, apb, aw, sTp);
  k_soft<<<BSZ * 256, 256, 0, stream>>>(x, sTp, pwa, pwab, pwoa, pwob,
                                        gam, bet, mu, var, poolw, poolb, h, s);
  k_topk<<<BSZ, 512, 0, stream>>>(s, h, out);
}